// Round 16
// baseline (204.018 us; speedup 1.0000x reference)
//
#include <hip/hip_runtime.h>

// PartialGConv: partial temporal conv (TK=9, pad 4) + mask-ratio + graph einsum.
// FUSED kernel (r13 geometry): bf16 implicit-GEMM (MFMA 16x16x32, BM=192 x
// BN=112(4t, 100 useful) x K=576), once-staged B window, MFMA contraction
// epilogue. r16: REGISTER-PIPELINED K-loop — af/bfr fragments for step ks+1
// are prefetched from LDS during step ks; the MFMA cluster runs purely on
// registers (no intra-step ds_read->MFMA stall). A(ks+2) staged at step ks
// (D=2 ring), VMCNT(0)+barrier at step end publishes it for the ks+1 prefetch.
// s_setprio(1) around the register-only MFMA cluster (T5).
//
// ws layout (bytes):
//   xmr  u16[32][6656][64]  @0          x*mask bf16 row-major, padded rows
//   wb   u16[192][576]      @27,262,976 weights bf16, k=dt*64+cin, 16B-slot swizzled
//   msum f32[32][6400]      @27,484,160 sum_cin mask
//   s    f32[32][6400]      @28,303,360 576/(upd+eps)*uc^2
//   mr   f32[32][6400]      @29,122,560 mask_ratio
//   mb   f32[32][6400]      @29,941,760 m_bool
//   Bc   f32[32][3][256][25]@30,760,960 sum_v uc*A[k,v,w]

typedef unsigned short u16;
typedef unsigned int u32;
typedef short short8 __attribute__((ext_vector_type(8)));
typedef float f32x4 __attribute__((ext_vector_type(4)));

#define TV 6400
#define KC 192
#define KDIM 576
#define NPADT 6656          // 100 front pad + 6400 + 156 back pad
#define Y_SIZE 13107200
#define MB_OFF 13109075     // Y_SIZE + 1875

#define OFF_WB   27262976
#define OFF_MSUM 27484160
#define OFF_S    28303360
#define OFF_MR   29122560
#define OFF_MB   29941760
#define OFF_BC   30760960

// LDS map (64,512 B). K-loop: xwin [0,39936) = 312 rows x 128B;
// A-ring [39936,64512) = 2 x 12,288.
// Epilogue aliases: Pl u16[64][168] @0 (21,504); Ys f32[32][104] @0;
// misc @39936: Ab 6144 | Bcs 1200 | mrs 400 | bias 768 | ss 400 | mbs 400.
#define L_ARING 39936
#define L_AB    39936
#define L_BCS   46080
#define L_MRS   47280
#define L_BIAS  47680
#define L_SS    48448
#define L_MBS   48848

#define VMCNT(N) asm volatile("s_waitcnt vmcnt(" #N ")" ::: "memory")
#define LGKMCNT0 asm volatile("s_waitcnt lgkmcnt(0)" ::: "memory")

__device__ __forceinline__ u16 f2bf(float f) {
  u32 u = __builtin_bit_cast(u32, f);
  u = (u + 0x7FFFu + ((u >> 16) & 1u)) >> 16;   // RTNE
  return (u16)u;
}
__device__ __forceinline__ float bf2f(u16 h) {
  return __builtin_bit_cast(float, (u32)h << 16);
}
__device__ __forceinline__ void gload_lds16(const u16* g, u16* l) {
  __builtin_amdgcn_global_load_lds(
      (const __attribute__((address_space(1))) u32*)(const void*)g,
      (__attribute__((address_space(3))) u32*)(void*)l, 16, 0, 0);
}

// ---- zero the temporal pad rows of xmr --------------------------------------
__global__ void k_pad(u16* __restrict__ xmr) {
  int i = blockIdx.x * 256 + threadIdx.x;       // 65536 uint4
  if (i >= 65536) return;
  int n = i >> 11, r = i & 2047;                // 256 pad rows x 8 uint4
  int row = r >> 3, c = r & 7;
  int tvrow = (row < 100) ? row : (6400 + row); // front 0..99 / back 6500..6655
  uint4 z; z.x = z.y = z.z = z.w = 0u;
  *(uint4*)(xmr + ((size_t)n * NPADT + tvrow) * 64 + c * 8) = z;
}

// ---- xmr = bf16(x*mask) row-major [tvp][64] + msum = sum_cin mask ------------
__global__ void k_xmT(const float* __restrict__ x, const float* __restrict__ mask,
                      u16* __restrict__ xmr, float* __restrict__ msum) {
  const int tvb = blockIdx.x, n = blockIdx.y;   // grid (100, 32), block 256
  const int tvl = threadIdx.x & 63, q = threadIdx.x >> 6;  // 4 quads of 16 cin
  const int tv = tvb * 64 + tvl;
  const float* xp = x + ((size_t)n * 64 + q * 16) * TV + tv;
  const float* mp = mask + ((size_t)n * 64 + q * 16) * TV + tv;
  u16 vals[16];
  float msacc = 0.f;
#pragma unroll
  for (int j = 0; j < 16; ++j) {                // coalesced: lanes = consecutive tv
    float xv = xp[(size_t)j * TV];
    float mv = mp[(size_t)j * TV];
    msacc += mv;
    vals[j] = f2bf(xv * mv);
  }
  uint4 lo, hi;
  lo.x = vals[0] | ((u32)vals[1] << 16);  lo.y = vals[2] | ((u32)vals[3] << 16);
  lo.z = vals[4] | ((u32)vals[5] << 16);  lo.w = vals[6] | ((u32)vals[7] << 16);
  hi.x = vals[8] | ((u32)vals[9] << 16);  hi.y = vals[10] | ((u32)vals[11] << 16);
  hi.z = vals[12] | ((u32)vals[13] << 16); hi.w = vals[14] | ((u32)vals[15] << 16);
  u16* dst = xmr + ((size_t)n * NPADT + 100 + tv) * 64 + q * 16;
  *(uint4*)dst = lo;
  *(uint4*)(dst + 8) = hi;
  __shared__ float red[4][64];
  red[q][tvl] = msacc;
  __syncthreads();
  if (q == 0) msum[n * TV + tv] = red[0][tvl] + red[1][tvl] + red[2][tvl] + red[3][tvl];
}

// ---- wb[kc][k=dt*64+cin], bf16, 16B-slot XOR pre-swizzle (by (kc>>1)&3) -----
__global__ void k_w(const float* __restrict__ weight, u16* __restrict__ wb) {
  int i = blockIdx.x * 256 + threadIdx.x;      // 110592
  if (i >= 110592) return;
  int kc = i / KDIM, k = i % KDIM;
  int cin = k & 63, dt = k >> 6;
  float v = weight[(kc * 64 + cin) * 9 + dt];
  int phys = (k & ~31) | ((((k >> 3) & 3) ^ ((kc >> 1) & 3)) << 3) | (k & 7);
  wb[kc * KDIM + phys] = f2bf(v);
}

// ---- per (n,t): upd -> s, mask_ratio, m_bool, Bc ----------------------------
__global__ void k_prep(const float* __restrict__ msum, const float* __restrict__ A_g,
                       float* __restrict__ s_ws, float* __restrict__ mr_ws,
                       float* __restrict__ mb_ws, float* __restrict__ Bc_ws) {
  int b = blockIdx.x;                          // 8192 = n*256 + t
  int n = b >> 8, t = b & 255;
  int tid = threadIdx.x;                       // 64
  __shared__ float uc[25];
  if (tid < 25) {
    float upd = 0.f;
    for (int dt = 0; dt < 9; ++dt) {
      int tt = t + dt - 4;
      if (tt >= 0 && tt < 256) upd += msum[n * TV + tt * 25 + tid];
    }
    float u_c = fminf(fmaxf(upd, 0.f), 1.f);
    float ratio = 576.f / (upd + 1e-8f);
    s_ws[n * TV + t * 25 + tid] = ratio * u_c * u_c;  // coeff of raw in out
    uc[tid] = u_c;
  }
  __syncthreads();
  if (tid < 25) {
    int w = tid;
    float M = 0.f;
    for (int k = 0; k < 3; ++k) {
      float acc = 0.f;
      for (int v = 0; v < 25; ++v) acc += uc[v] * A_g[(k * 25 + v) * 25 + w];
      Bc_ws[((size_t)(n * 3 + k) * 256 + t) * 25 + w] = acc;
      M += acc;
    }
    float mbv = (M != 0.f) ? 1.f : 0.f;
    mr_ws[n * TV + t * 25 + w] = mbv / (M + 1e-8f);
    mb_ws[n * TV + t * 25 + w] = mbv;
  }
}

// ---- FUSED: implicit-GEMM + MFMA (k,v)-contraction + coalesced epilogue -----
// Block (tg, n): 512 threads, 8 waves = 4(M) x 2(N). Wave cols: wn=0 -> 4
// frags (0-63), wn=1 -> 3 frags (64-111; 100-111 dead, guarded at P-stage).
// K-loop: register-pipelined — step ks prefetches af/bfr(ks+1) from LDS and
// runs MFMAs purely on regs read at ks-1; stages A(ks+2); VMCNT(0)+barrier.
__global__ __launch_bounds__(512, 3) void k_fused(
    const u16* __restrict__ xmr, const u16* __restrict__ wb,
    const float* __restrict__ s_g, const float* __restrict__ A_g,
    const float* __restrict__ Bc_g, const float* __restrict__ mr_g,
    const float* __restrict__ mb_g, const float* __restrict__ bias_g,
    float* __restrict__ out) {
  __shared__ __align__(16) char ring[64512];

  const int tid = threadIdx.x;
  const int tg = blockIdx.x;                  // 0..63 (4-t group)
  const int n = blockIdx.y;                   // 0..31
  const int T = tg * 100;                     // window start (padded coords)
  const int lane = tid & 63, wid = tid >> 6;
  const int wm = wid >> 1, wn = wid & 1;
  const int lrow = lane & 15, lgrp = lane >> 4;
  const int nf = 4 - wn, colb = wn * 64;

  const u16* xmn = xmr + (size_t)n * NPADT * 64;
  u16* xwin = (u16*)(ring);

  f32x4 acc[3][4] = {};

  // A staging: 12 tile-loads spread as waves 0-3: 2, waves 4-7: 1.
  auto stageA = [&](int buf, int ks) {
    u16* abase = (u16*)(ring + L_ARING + buf * 12288);
#pragma unroll
    for (int j = 0; j < 2; ++j) {
      int task = wid + j * 8;
      if (task < 12) {
        const u16* src = wb + (size_t)(task * 16 + (lane >> 2)) * KDIM + ks * 32 + (lane & 3) * 8;
        gload_lds16(src, abase + task * 512);
      }
    }
  };
  // Register fragment loads for step ks (A from ring buf, B from xwin).
  auto loadA = [&](short8* af, int buf) {
    const u16* abuf = (const u16*)(ring + L_ARING + buf * 12288);
#pragma unroll
    for (int m = 0; m < 3; ++m) {
      int arow = wm * 48 + m * 16 + lrow;
      af[m] = *(const short8*)&abuf[(arow)*32 + ((lgrp ^ ((arow >> 1) & 3)) << 3)];
    }
  };
  auto loadB = [&](short8* bf, int ks) {
    const int dt = ks >> 1;
    const int rbase = 100 + (dt - 4) * 25 + colb + lrow;
    const int slb = (ks & 1) * 4 + lgrp;
#pragma unroll
    for (int ct = 0; ct < 4; ++ct) {
      if (ct < nf) {
        int srow = rbase + ct * 16;
        bf[ct] = *(const short8*)&xwin[srow * 64 + ((slb ^ (srow & 7)) << 3)];
      }
    }
  };

  // ---- prologue: stage B window (39 loads) + A(0), A(1) ---------------------
  {
    // LDS[row][slot] = global[row][slot ^ (row&7)] in WINDOW coords.
    const int srow_g = lane >> 3, sl = (lane & 7) ^ (lane >> 3);  // per-lane
    for (int t = wid; t < 39; t += 8) {
      const u16* src = xmn + ((size_t)(T + t * 8 + srow_g) * 64 + sl * 8);
      gload_lds16(src, xwin + t * 512);
    }
    stageA(0, 0);
    stageA(1, 1);
  }
  VMCNT(0);
  __builtin_amdgcn_s_barrier();
  asm volatile("" ::: "memory");

  short8 af_c[3], af_n[3], bf_c[4], bf_n[4];
  loadA(af_c, 0);
  loadB(bf_c, 0);
  LGKMCNT0;                          // secure regs before buf0 is restaged

  // ---- K-loop: 18 steps, register-pipelined ---------------------------------
  // Top-of-step invariant: af_c/bf_c hold step-ks fragments (read at ks-1);
  // A(ks+1) is in LDS buf[(ks+1)&1] (staged at ks-1, published by the ks-1
  // barrier). Step ks: prefetch (ks+1) frags, stage A(ks+2) into buf[ks&1]
  // (its A(ks) content was secured into regs by ALL waves before the ks-1
  // barrier), MFMA on regs, then VMCNT(0)+barrier publishes A(ks+2).
#pragma unroll 2
  for (int ks = 0; ks < 18; ++ks) {
    if (ks < 17) {
      loadA(af_n, (ks + 1) & 1);
      loadB(bf_n, ks + 1);
    }
    if (ks < 16) stageA(ks & 1, ks + 2);

    __builtin_amdgcn_s_setprio(1);
#pragma unroll
    for (int ct = 0; ct < 4; ++ct) {
      if (ct < nf) {
#pragma unroll
        for (int m = 0; m < 3; ++m)
          acc[m][ct] = __builtin_amdgcn_mfma_f32_16x16x32_bf16(af_c[m], bf_c[ct], acc[m][ct], 0, 0, 0);
      }
    }
    __builtin_amdgcn_s_setprio(0);

#pragma unroll
    for (int m = 0; m < 3; ++m) af_c[m] = af_n[m];
#pragma unroll
    for (int ct = 0; ct < 4; ++ct) bf_c[ct] = bf_n[ct];

    if (ks < 16) {
      VMCNT(0);                      // own A(ks+2) loads landed (MFMA phase cover)
      __builtin_amdgcn_s_barrier();
      asm volatile("" ::: "memory");
    }
  }

  // ---- epilogue setup: zero Pl, stage Ab/Bcs/mrs/bias/ss/mbs ---------------
  __syncthreads();                     // all xwin/abuf reads done; safe to alias
  u16*   Plu   = (u16*)ring;           // [64][168]: tcol = t*40+v, pads zero
  u16*   Abu   = (u16*)(ring + L_AB);  // [3k][2nt][16w][32v] bf16 B-frag layout
  float* Bcsf  = (float*)(ring + L_BCS);
  float* mrsf  = (float*)(ring + L_MRS);
  float* biasf = (float*)(ring + L_BIAS);
  float* ssf   = (float*)(ring + L_SS);
  float* mbsf  = (float*)(ring + L_MBS);
  {
    uint4 z; z.x = z.y = z.z = z.w = 0u;
    for (int i = tid; i < 1344; i += 512) ((uint4*)ring)[i] = z;  // zero Pl
  }
  for (int i = tid; i < 3072; i += 512) {
    int kk = i >> 10, r = i & 1023;
    int nt = r >> 9, rr = r & 511, wl = rr >> 5, v = rr & 31;
    int w = nt * 16 + wl;
    float val = (v < 25 && w < 25) ? A_g[(kk * 25 + v) * 25 + w] : 0.f;
    Abu[i] = f2bf(val);
  }
  if (tid < 300) {
    int k = tid / 100, t = (tid % 100) / 25, w = tid % 25;
    Bcsf[tid] = Bc_g[((size_t)(n * 3 + k) * 256 + tg * 4 + t) * 25 + w];
  }
  if (tid < 100) {
    mrsf[tid] = mr_g[n * TV + T + tid];
    ssf[tid]  = s_g[n * TV + T + tid];
    mbsf[tid] = mb_g[n * TV + T + tid];
  }
  if (tid >= 256 && tid < 448) biasf[tid - 256] = bias_g[tid - 256];
  __syncthreads();

  // ---- MFMA contraction: y(ct,w) = sum_v P(ct,v) * A(v,w), per-k -----------
  f32x4 yacc[2][2] = {};
  for (int k = 0; k < 3; ++k) {
    // stage Pl_k = bf16(acc * s) for rows of this k
#pragma unroll
    for (int m = 0; m < 3; ++m) {
      int R = wm * 48 + m * 16 + lgrp * 4;
      if ((R >> 6) == k) {
        int cb = R & 63;
#pragma unroll
        for (int ct = 0; ct < 4; ++ct) {
          if (ct < nf) {
            int col = colb + ct * 16 + lrow;
            if (col < 100) {
              int t = col / 25, v = col - t * 25;
              float sv = ssf[col];
              int tc = t * 40 + v;
#pragma unroll
              for (int r = 0; r < 4; ++r)
                Plu[(cb + r) * 168 + tc] = f2bf(acc[m][ct][r] * sv);
            }
          }
        }
      }
    }
    __syncthreads();
    // contraction MFMAs: wave owns M-tiles {wid*2, wid*2+1} (16 tiles of 16 ct)
    short8 pb[2];
#pragma unroll
    for (int nt = 0; nt < 2; ++nt)
      pb[nt] = *(const short8*)&Abu[((k * 2 + nt) * 16 + lrow) * 32 + lgrp * 8];
#pragma unroll
    for (int mi = 0; mi < 2; ++mi) {
      int mt = wid * 2 + mi;
      // A-row = mt*16 + lrow = ct; c = mt*4 + (lrow>>2), t = lrow&3
      const short8 pa = *(const short8*)
          &Plu[(mt * 4 + (lrow >> 2)) * 168 + (lrow & 3) * 40 + lgrp * 8];
#pragma unroll
      for (int nt = 0; nt < 2; ++nt)
        yacc[mi][nt] = __builtin_amdgcn_mfma_f32_16x16x32_bf16(pa, pb[nt], yacc[mi][nt], 0, 0, 0);
    }
    __syncthreads();                   // before next k overwrites Pl
  }

  // ---- finalize + transposed coalesced y writes ----------------------------
  // yacc[mi][nt][r]: ct = (wid*2+mi)*16 + lgrp*4 + r -> c = wid*8+mi*4+lgrp,
  // t = r; col w = nt*16 + lrow.
  float (*Ysf)[104] = (float(*)[104])ring;     // aliases Pl, barrier-separated
  const size_t base_n = (size_t)(n * 64) * 6400 + T;
#pragma unroll
  for (int half = 0; half < 2; ++half) {
    __syncthreads();
    if ((wid >> 2) == half) {
#pragma unroll
      for (int mi = 0; mi < 2; ++mi) {
        int c = wid * 8 + mi * 4 + lgrp;       // 0..63
#pragma unroll
        for (int nt = 0; nt < 2; ++nt) {
          int w = nt * 16 + lrow;
          if (w < 25) {
#pragma unroll
            for (int r = 0; r < 4; ++r) {
              float bt = biasf[c] * Bcsf[r * 25 + w] +
                         biasf[64 + c] * Bcsf[100 + r * 25 + w] +
                         biasf[128 + c] * Bcsf[200 + r * 25 + w];
              Ysf[c & 31][r * 25 + w] = (yacc[mi][nt][r] + bt) * mrsf[r * 25 + w];
            }
          }
        }
      }
    }
    __syncthreads();
    for (int i = tid; i < 3200; i += 512) {
      int ch = i / 100, j = i % 100;
      out[base_n + (size_t)(half * 32 + ch) * 6400 + j] = Ysf[ch][j];
    }
  }

  // m_bool: c-independent broadcast, direct coalesced stores
  for (int i = tid; i < 6400; i += 512) {
    int cc = i / 100, j = i % 100;
    out[MB_OFF + base_n + (size_t)cc * 6400 + j] = mbsf[j];
  }
}

extern "C" void kernel_launch(void* const* d_in, const int* in_sizes, int n_in,
                              void* d_out, int out_size, void* d_ws, size_t ws_size,
                              hipStream_t stream) {
  const float* x      = (const float*)d_in[0];
  const float* A      = (const float*)d_in[1];
  const float* mask   = (const float*)d_in[2];
  const float* weight = (const float*)d_in[3];
  const float* bias   = (const float*)d_in[4];
  float* out = (float*)d_out;
  char* ws = (char*)d_ws;

  u16*   xmr   = (u16*)(ws);
  u16*   wb    = (u16*)(ws + OFF_WB);
  float* msum  = (float*)(ws + OFF_MSUM);
  float* s_ws  = (float*)(ws + OFF_S);
  float* mr_ws = (float*)(ws + OFF_MR);
  float* mb_ws = (float*)(ws + OFF_MB);
  float* Bc_ws = (float*)(ws + OFF_BC);

  k_pad<<<256, 256, 0, stream>>>(xmr);
  k_xmT<<<dim3(100, 32), 256, 0, stream>>>(x, mask, xmr, msum);
  k_w<<<432, 256, 0, stream>>>(weight, wb);
  k_prep<<<8192, 64, 0, stream>>>(msum, A, s_ws, mr_ws, mb_ws, Bc_ws);

  hipMemcpyAsync(out + Y_SIZE, A, 1875 * sizeof(float),
                 hipMemcpyDeviceToDevice, stream);

  k_fused<<<dim3(64, 32), 512, 0, stream>>>(xmr, wb, s_ws, A, Bc_ws, mr_ws,
                                            mb_ws, bias, out);
}

// Round 17
// 131.302 us; speedup vs baseline: 1.5538x; 1.5538x over previous
//
#include <hip/hip_runtime.h>

// PartialGConv: partial temporal conv (TK=9, pad 4) + mask-ratio + graph einsum.
// FUSED kernel (r14 structure, best measured): bf16 implicit-GEMM (MFMA
// 16x16x32, BM=192 x BN=112(4t, 100 useful) x K=576), once-staged B window,
// 3-buffer A-ring with depth-2 counted vmcnt, MFMA contraction epilogue,
// 2 blocks/CU. r17: + bijective XCD swizzle (consecutive-tg blocks share 67%
// of their B window + all of wb -> cluster them on one XCD's L2), and k_pad
// fused into k_xmT (one fewer dispatch).
//
// ws layout (bytes):
//   xmr  u16[32][6656][64]  @0          x*mask bf16 row-major, padded rows
//   wb   u16[192][576]      @27,262,976 weights bf16, k=dt*64+cin, 16B-slot swizzled
//   msum f32[32][6400]      @27,484,160 sum_cin mask
//   s    f32[32][6400]      @28,303,360 576/(upd+eps)*uc^2
//   mr   f32[32][6400]      @29,122,560 mask_ratio
//   mb   f32[32][6400]      @29,941,760 m_bool
//   Bc   f32[32][3][256][25]@30,760,960 sum_v uc*A[k,v,w]

typedef unsigned short u16;
typedef unsigned int u32;
typedef short short8 __attribute__((ext_vector_type(8)));
typedef float f32x4 __attribute__((ext_vector_type(4)));

#define TV 6400
#define KC 192
#define KDIM 576
#define NPADT 6656          // 100 front pad + 6400 + 156 back pad
#define Y_SIZE 13107200
#define MB_OFF 13109075     // Y_SIZE + 1875

#define OFF_WB   27262976
#define OFF_MSUM 27484160
#define OFF_S    28303360
#define OFF_MR   29122560
#define OFF_MB   29941760
#define OFF_BC   30760960

// LDS map (76,800 B = exactly 2 blocks/CU). K-loop: xwin [0,39936) =
// 312 rows x 128B; A-ring [39936,76800) = 3 x 12,288 (ring depth 3).
// Epilogue aliases: Pl u16[64][168] @0 (21,504); Ys f32[32][104] @0;
// misc @39936: Ab 6144 | Bcs 1200 | mrs 400 | bias 768 | ss 400 | mbs 400.
#define L_ARING 39936
#define L_AB    39936
#define L_BCS   46080
#define L_MRS   47280
#define L_BIAS  47680
#define L_SS    48448
#define L_MBS   48848

#define VMCNT(N) asm volatile("s_waitcnt vmcnt(" #N ")" ::: "memory")

__device__ __forceinline__ u16 f2bf(float f) {
  u32 u = __builtin_bit_cast(u32, f);
  u = (u + 0x7FFFu + ((u >> 16) & 1u)) >> 16;   // RTNE
  return (u16)u;
}
__device__ __forceinline__ float bf2f(u16 h) {
  return __builtin_bit_cast(float, (u32)h << 16);
}
__device__ __forceinline__ void gload_lds16(const u16* g, u16* l) {
  __builtin_amdgcn_global_load_lds(
      (const __attribute__((address_space(1))) u32*)(const void*)g,
      (__attribute__((address_space(3))) u32*)(void*)l, 16, 0, 0);
}

// ---- xmr = bf16(x*mask) row-major [tvp][64] + msum; pads via extra blocks ---
__global__ void k_xmT(const float* __restrict__ x, const float* __restrict__ mask,
                      u16* __restrict__ xmr, float* __restrict__ msum) {
  const int tvb = blockIdx.x, n = blockIdx.y;   // grid (104, 32), block 256
  if (tvb >= 100) {                             // pad blocks: zero 256 pad rows
    for (int j = (tvb - 100) * 256 + threadIdx.x; j < 2048; j += 1024) {
      int row = j >> 3, c = j & 7;              // 256 rows x 8 uint4
      int tvrow = (row < 100) ? row : (6400 + row);
      uint4 z; z.x = z.y = z.z = z.w = 0u;
      *(uint4*)(xmr + ((size_t)n * NPADT + tvrow) * 64 + c * 8) = z;
    }
    return;
  }
  const int tvl = threadIdx.x & 63, q = threadIdx.x >> 6;  // 4 quads of 16 cin
  const int tv = tvb * 64 + tvl;
  const float* xp = x + ((size_t)n * 64 + q * 16) * TV + tv;
  const float* mp = mask + ((size_t)n * 64 + q * 16) * TV + tv;
  u16 vals[16];
  float msacc = 0.f;
#pragma unroll
  for (int j = 0; j < 16; ++j) {                // coalesced: lanes = consecutive tv
    float xv = xp[(size_t)j * TV];
    float mv = mp[(size_t)j * TV];
    msacc += mv;
    vals[j] = f2bf(xv * mv);
  }
  uint4 lo, hi;
  lo.x = vals[0] | ((u32)vals[1] << 16);  lo.y = vals[2] | ((u32)vals[3] << 16);
  lo.z = vals[4] | ((u32)vals[5] << 16);  lo.w = vals[6] | ((u32)vals[7] << 16);
  hi.x = vals[8] | ((u32)vals[9] << 16);  hi.y = vals[10] | ((u32)vals[11] << 16);
  hi.z = vals[12] | ((u32)vals[13] << 16); hi.w = vals[14] | ((u32)vals[15] << 16);
  u16* dst = xmr + ((size_t)n * NPADT + 100 + tv) * 64 + q * 16;
  *(uint4*)dst = lo;
  *(uint4*)(dst + 8) = hi;
  __shared__ float red[4][64];
  red[q][tvl] = msacc;
  __syncthreads();
  if (q == 0) msum[n * TV + tv] = red[0][tvl] + red[1][tvl] + red[2][tvl] + red[3][tvl];
}

// ---- wb[kc][k=dt*64+cin], bf16, 16B-slot XOR pre-swizzle (by (kc>>1)&3) -----
__global__ void k_w(const float* __restrict__ weight, u16* __restrict__ wb) {
  int i = blockIdx.x * 256 + threadIdx.x;      // 110592
  if (i >= 110592) return;
  int kc = i / KDIM, k = i % KDIM;
  int cin = k & 63, dt = k >> 6;
  float v = weight[(kc * 64 + cin) * 9 + dt];
  int phys = (k & ~31) | ((((k >> 3) & 3) ^ ((kc >> 1) & 3)) << 3) | (k & 7);
  wb[kc * KDIM + phys] = f2bf(v);
}

// ---- per (n,t): upd -> s, mask_ratio, m_bool, Bc ----------------------------
__global__ void k_prep(const float* __restrict__ msum, const float* __restrict__ A_g,
                       float* __restrict__ s_ws, float* __restrict__ mr_ws,
                       float* __restrict__ mb_ws, float* __restrict__ Bc_ws) {
  int b = blockIdx.x;                          // 8192 = n*256 + t
  int n = b >> 8, t = b & 255;
  int tid = threadIdx.x;                       // 64
  __shared__ float uc[25];
  if (tid < 25) {
    float upd = 0.f;
    for (int dt = 0; dt < 9; ++dt) {
      int tt = t + dt - 4;
      if (tt >= 0 && tt < 256) upd += msum[n * TV + tt * 25 + tid];
    }
    float u_c = fminf(fmaxf(upd, 0.f), 1.f);
    float ratio = 576.f / (upd + 1e-8f);
    s_ws[n * TV + t * 25 + tid] = ratio * u_c * u_c;  // coeff of raw in out
    uc[tid] = u_c;
  }
  __syncthreads();
  if (tid < 25) {
    int w = tid;
    float M = 0.f;
    for (int k = 0; k < 3; ++k) {
      float acc = 0.f;
      for (int v = 0; v < 25; ++v) acc += uc[v] * A_g[(k * 25 + v) * 25 + w];
      Bc_ws[((size_t)(n * 3 + k) * 256 + t) * 25 + w] = acc;
      M += acc;
    }
    float mbv = (M != 0.f) ? 1.f : 0.f;
    mr_ws[n * TV + t * 25 + w] = mbv / (M + 1e-8f);
    mb_ws[n * TV + t * 25 + w] = mbv;
  }
}

// ---- FUSED: implicit-GEMM + MFMA (k,v)-contraction + coalesced epilogue -----
// Block (tg, n) via bijective XCD swizzle: consecutive-tg blocks (67% window
// overlap + shared wb) cluster on one XCD's L2. 512 threads, 8 waves =
// 4(M) x 2(N); 3-buffer A-ring, depth-2 prefetch, counted vmcnt, 1 barrier/step.
__global__ __launch_bounds__(512, 4) void k_fused(
    const u16* __restrict__ xmr, const u16* __restrict__ wb,
    const float* __restrict__ s_g, const float* __restrict__ A_g,
    const float* __restrict__ Bc_g, const float* __restrict__ mr_g,
    const float* __restrict__ mb_g, const float* __restrict__ bias_g,
    float* __restrict__ out) {
  __shared__ __align__(16) char ring[76800];

  const int tid = threadIdx.x;
  // XCD swizzle: nwg = 2048 = 8 XCDs x 256; bijective since 2048 % 8 == 0.
  const int flat = blockIdx.y * 64 + blockIdx.x;
  const int swz = (flat & 7) * 256 + (flat >> 3);
  const int tg = swz & 63;                    // 0..63 (4-t group)
  const int n = swz >> 6;                     // 0..31
  const int T = tg * 100;                     // window start (padded coords)
  const int lane = tid & 63, wid = tid >> 6;
  const int wm = wid >> 1, wn = wid & 1;
  const int lrow = lane & 15, lgrp = lane >> 4;
  const int nf = 4 - wn, colb = wn * 64;

  const u16* xmn = xmr + (size_t)n * NPADT * 64;
  u16* xwin = (u16*)(ring);

  f32x4 acc[3][4] = {};

  // A staging helper: 12 tile-loads spread as waves 0-3: 2, waves 4-7: 1.
  auto stageA = [&](int buf, int ks) {
    u16* abase = (u16*)(ring + L_ARING + buf * 12288);
#pragma unroll
    for (int j = 0; j < 2; ++j) {
      int task = wid + j * 8;
      if (task < 12) {
        const u16* src = wb + (size_t)(task * 16 + (lane >> 2)) * KDIM + ks * 32 + (lane & 3) * 8;
        gload_lds16(src, abase + task * 512);
      }
    }
  };

  // ---- prologue: stage B window (39 loads) + A steps 0,1 --------------------
  {
    // LDS[row][slot] = global[row][slot ^ (row&7)] in WINDOW coords.
    const int srow_g = lane >> 3, sl = (lane & 7) ^ (lane >> 3);  // per-lane
    for (int t = wid; t < 39; t += 8) {
      const u16* src = xmn + ((size_t)(T + t * 8 + srow_g) * 64 + sl * 8);
      gload_lds16(src, xwin + t * 512);
    }
    stageA(0, 0);
    stageA(1, 1);
  }
  VMCNT(0);
  __builtin_amdgcn_s_barrier();
  asm volatile("" ::: "memory");

  // ---- K-loop: 18 steps; depth-2 counted-vmcnt pipeline ---------------------
  // Invariant at top of step ks: buf[ks%3] data landed for ALL waves (each
  // wave waited for its own step-ks loads via VMCNT before the prior barrier,
  // and the barrier published them). Staging buf[(ks+2)%3] overwrites
  // buf[(ks-1)%3]: safe — every wave finished its ks-1 ds_reads before the
  // barrier (lgkmcnt before MFMA use, MFMA before barrier in program order).
  for (int ks = 0; ks < 18; ++ks) {
    if (ks < 16) stageA((ks + 2) % 3, ks + 2);

    const u16* abuf = (const u16*)(ring + L_ARING + (ks % 3) * 12288);
    short8 af[3];
#pragma unroll
    for (int m = 0; m < 3; ++m) {
      int arow = wm * 48 + m * 16 + lrow;
      af[m] = *(const short8*)&abuf[arow * 32 + ((lgrp ^ ((arow >> 1) & 3)) << 3)];
    }
    const int dt = ks >> 1;
    const int rbase = 100 + (dt - 4) * 25 + colb + lrow;   // window row for ct=0
    const int slb = (ks & 1) * 4 + lgrp;                   // logical 16B slot
#pragma unroll
    for (int ct = 0; ct < 4; ++ct) {
      if (ct < nf) {
        int srow = rbase + ct * 16;
        short8 bfr = *(const short8*)&xwin[srow * 64 + ((slb ^ (srow & 7)) << 3)];
#pragma unroll
        for (int m = 0; m < 3; ++m)
          acc[m][ct] = __builtin_amdgcn_mfma_f32_16x16x32_bf16(af[m], bfr, acc[m][ct], 0, 0, 0);
      }
    }

    if (ks < 16) {
      // wait for step-(ks+1) loads (issued at ks-1); allow my just-issued
      // step-(ks+2) loads (S of them) to stay in flight.  S: waves 0-3 = 2,
      // waves 4-7 = 1.  vmcnt is wave-uniform (wid is wave-uniform).
      if (wid < 4) VMCNT(2); else VMCNT(1);
      __builtin_amdgcn_s_barrier();
      asm volatile("" ::: "memory");
    } else if (ks == 16) {
      VMCNT(0);                        // last loads (step 17, issued at 15)
      __builtin_amdgcn_s_barrier();
      asm volatile("" ::: "memory");
    }
  }

  // ---- epilogue setup: zero Pl, stage Ab/Bcs/mrs/bias/ss/mbs ---------------
  __syncthreads();                     // all xwin/abuf reads done; safe to alias
  u16*   Plu   = (u16*)ring;           // [64][168]: tcol = t*40+v, pads zero
  u16*   Abu   = (u16*)(ring + L_AB);  // [3k][2nt][16w][32v] bf16 B-frag layout
  float* Bcsf  = (float*)(ring + L_BCS);
  float* mrsf  = (float*)(ring + L_MRS);
  float* biasf = (float*)(ring + L_BIAS);
  float* ssf   = (float*)(ring + L_SS);
  float* mbsf  = (float*)(ring + L_MBS);
  {
    uint4 z; z.x = z.y = z.z = z.w = 0u;
    for (int i = tid; i < 1344; i += 512) ((uint4*)ring)[i] = z;  // zero Pl
  }
  for (int i = tid; i < 3072; i += 512) {
    int kk = i >> 10, r = i & 1023;
    int nt = r >> 9, rr = r & 511, wl = rr >> 5, v = rr & 31;
    int w = nt * 16 + wl;
    float val = (v < 25 && w < 25) ? A_g[(kk * 25 + v) * 25 + w] : 0.f;
    Abu[i] = f2bf(val);
  }
  if (tid < 300) {
    int k = tid / 100, t = (tid % 100) / 25, w = tid % 25;
    Bcsf[tid] = Bc_g[((size_t)(n * 3 + k) * 256 + tg * 4 + t) * 25 + w];
  }
  if (tid < 100) {
    mrsf[tid] = mr_g[n * TV + T + tid];
    ssf[tid]  = s_g[n * TV + T + tid];
    mbsf[tid] = mb_g[n * TV + T + tid];
  }
  if (tid >= 256 && tid < 448) biasf[tid - 256] = bias_g[tid - 256];
  __syncthreads();

  // ---- MFMA contraction: y(ct,w) = sum_v P(ct,v) * A(v,w), per-k -----------
  f32x4 yacc[2][2] = {};
  for (int k = 0; k < 3; ++k) {
    // stage Pl_k = bf16(acc * s) for rows of this k
#pragma unroll
    for (int m = 0; m < 3; ++m) {
      int R = wm * 48 + m * 16 + lgrp * 4;
      if ((R >> 6) == k) {
        int cb = R & 63;
#pragma unroll
        for (int ct = 0; ct < 4; ++ct) {
          if (ct < nf) {
            int col = colb + ct * 16 + lrow;
            if (col < 100) {
              int t = col / 25, v = col - t * 25;
              float sv = ssf[col];
              int tc = t * 40 + v;
#pragma unroll
              for (int r = 0; r < 4; ++r)
                Plu[(cb + r) * 168 + tc] = f2bf(acc[m][ct][r] * sv);
            }
          }
        }
      }
    }
    __syncthreads();
    // contraction MFMAs: wave owns M-tiles {wid*2, wid*2+1} (16 tiles of 16 ct)
    short8 pb[2];
#pragma unroll
    for (int nt = 0; nt < 2; ++nt)
      pb[nt] = *(const short8*)&Abu[((k * 2 + nt) * 16 + lrow) * 32 + lgrp * 8];
#pragma unroll
    for (int mi = 0; mi < 2; ++mi) {
      int mt = wid * 2 + mi;
      // A-row = mt*16 + lrow = ct; c = mt*4 + (lrow>>2), t = lrow&3
      const short8 pa = *(const short8*)
          &Plu[(mt * 4 + (lrow >> 2)) * 168 + (lrow & 3) * 40 + lgrp * 8];
#pragma unroll
      for (int nt = 0; nt < 2; ++nt)
        yacc[mi][nt] = __builtin_amdgcn_mfma_f32_16x16x32_bf16(pa, pb[nt], yacc[mi][nt], 0, 0, 0);
    }
    __syncthreads();                   // before next k overwrites Pl
  }

  // ---- finalize + transposed coalesced y writes ----------------------------
  // yacc[mi][nt][r]: ct = (wid*2+mi)*16 + lgrp*4 + r -> c = wid*8+mi*4+lgrp,
  // t = r; col w = nt*16 + lrow.
  float (*Ysf)[104] = (float(*)[104])ring;     // aliases Pl, barrier-separated
  const size_t base_n = (size_t)(n * 64) * 6400 + T;
#pragma unroll
  for (int half = 0; half < 2; ++half) {
    __syncthreads();
    if ((wid >> 2) == half) {
#pragma unroll
      for (int mi = 0; mi < 2; ++mi) {
        int c = wid * 8 + mi * 4 + lgrp;       // 0..63
#pragma unroll
        for (int nt = 0; nt < 2; ++nt) {
          int w = nt * 16 + lrow;
          if (w < 25) {
#pragma unroll
            for (int r = 0; r < 4; ++r) {
              float bt = biasf[c] * Bcsf[r * 25 + w] +
                         biasf[64 + c] * Bcsf[100 + r * 25 + w] +
                         biasf[128 + c] * Bcsf[200 + r * 25 + w];
              Ysf[c & 31][r * 25 + w] = (yacc[mi][nt][r] + bt) * mrsf[r * 25 + w];
            }
          }
        }
      }
    }
    __syncthreads();
    for (int i = tid; i < 3200; i += 512) {
      int ch = i / 100, j = i % 100;
      out[base_n + (size_t)(half * 32 + ch) * 6400 + j] = Ysf[ch][j];
    }
  }

  // m_bool: c-independent broadcast, direct coalesced stores
  for (int i = tid; i < 6400; i += 512) {
    int cc = i / 100, j = i % 100;
    out[MB_OFF + base_n + (size_t)cc * 6400 + j] = mbsf[j];
  }
}

extern "C" void kernel_launch(void* const* d_in, const int* in_sizes, int n_in,
                              void* d_out, int out_size, void* d_ws, size_t ws_size,
                              hipStream_t stream) {
  const float* x      = (const float*)d_in[0];
  const float* A      = (const float*)d_in[1];
  const float* mask   = (const float*)d_in[2];
  const float* weight = (const float*)d_in[3];
  const float* bias   = (const float*)d_in[4];
  float* out = (float*)d_out;
  char* ws = (char*)d_ws;

  u16*   xmr   = (u16*)(ws);
  u16*   wb    = (u16*)(ws + OFF_WB);
  float* msum  = (float*)(ws + OFF_MSUM);
  float* s_ws  = (float*)(ws + OFF_S);
  float* mr_ws = (float*)(ws + OFF_MR);
  float* mb_ws = (float*)(ws + OFF_MB);
  float* Bc_ws = (float*)(ws + OFF_BC);

  k_xmT<<<dim3(104, 32), 256, 0, stream>>>(x, mask, xmr, msum);
  k_w<<<432, 256, 0, stream>>>(weight, wb);
  k_prep<<<8192, 64, 0, stream>>>(msum, A, s_ws, mr_ws, mb_ws, Bc_ws);

  hipMemcpyAsync(out + Y_SIZE, A, 1875 * sizeof(float),
                 hipMemcpyDeviceToDevice, stream);

  k_fused<<<dim3(64, 32), 512, 0, stream>>>(xmr, wb, s_ws, A, Bc_ws, mr_ws,
                                            mb_ws, bias, out);
}

// Round 18
// 119.920 us; speedup vs baseline: 1.7013x; 1.0949x over previous
//
#include <hip/hip_runtime.h>

// PartialGConv: partial temporal conv (TK=9, pad 4) + mask-ratio + graph einsum.
// FUSED kernel (r17 = r14+XCD-swizzle, best measured): bf16 implicit-GEMM
// (MFMA 16x16x32, BM=192 x BN=112(4t, 100 useful) x K=576), once-staged B
// window, LDS A-ring, MFMA contraction epilogue, 2 blocks/CU, bijective XCD
// swizzle. r18: ALL epilogue misc (Abu/Bcs/mrs/bias/ss/mbs) staged in the
// PROLOGUE into a private LDS region (latency hidden under window staging;
// epilogue setup collapses to zero-Pl + 1 barrier). Ring depth 3->2 to fit
// (depth-2-drain == depth-3-counted, r13 vs r14). k_prep packs 2 t per block.
//
// ws layout (bytes):
//   xmr  u16[32][6656][64]  @0          x*mask bf16 row-major, padded rows
//   wb   u16[192][576]      @27,262,976 weights bf16, k=dt*64+cin, 16B-slot swizzled
//   msum f32[32][6400]      @27,484,160 sum_cin mask
//   s    f32[32][6400]      @28,303,360 576/(upd+eps)*uc^2
//   mr   f32[32][6400]      @29,122,560 mask_ratio
//   mb   f32[32][6400]      @29,941,760 m_bool
//   Bc   f32[32][3][256][25]@30,760,960 sum_v uc*A[k,v,w]

typedef unsigned short u16;
typedef unsigned int u32;
typedef short short8 __attribute__((ext_vector_type(8)));
typedef float f32x4 __attribute__((ext_vector_type(4)));

#define TV 6400
#define KC 192
#define KDIM 576
#define NPADT 6656          // 100 front pad + 6400 + 156 back pad
#define Y_SIZE 13107200
#define MB_OFF 13109075     // Y_SIZE + 1875

#define OFF_WB   27262976
#define OFF_MSUM 27484160
#define OFF_S    28303360
#define OFF_MR   29122560
#define OFF_MB   29941760
#define OFF_BC   30760960

// LDS map (73,824 B total -> 2 blocks/CU). K-loop: xwin [0,39936) =
// 312 rows x 128B; A-ring [39936,64512) = 2 x 12,288.
// Misc (PROLOGUE-staged, never aliased): Ab @64512 (6144) | Bcs @70656 (1200)
// | mrs @71856 (400) | bias @72256 (768) | ss @73024 (400) | mbs @73424 (400).
// Epilogue aliases (xwin only): Pl u16[64][168] @0 (21,504); Ys f32[32][104] @0.
#define L_ARING 39936
#define L_AB    64512
#define L_BCS   70656
#define L_MRS   71856
#define L_BIAS  72256
#define L_SS    73024
#define L_MBS   73424

#define VMCNT(N) asm volatile("s_waitcnt vmcnt(" #N ")" ::: "memory")

__device__ __forceinline__ u16 f2bf(float f) {
  u32 u = __builtin_bit_cast(u32, f);
  u = (u + 0x7FFFu + ((u >> 16) & 1u)) >> 16;   // RTNE
  return (u16)u;
}
__device__ __forceinline__ float bf2f(u16 h) {
  return __builtin_bit_cast(float, (u32)h << 16);
}
__device__ __forceinline__ void gload_lds16(const u16* g, u16* l) {
  __builtin_amdgcn_global_load_lds(
      (const __attribute__((address_space(1))) u32*)(const void*)g,
      (__attribute__((address_space(3))) u32*)(void*)l, 16, 0, 0);
}

// ---- xmr = bf16(x*mask) row-major [tvp][64] + msum; pads via extra blocks ---
__global__ void k_xmT(const float* __restrict__ x, const float* __restrict__ mask,
                      u16* __restrict__ xmr, float* __restrict__ msum) {
  const int tvb = blockIdx.x, n = blockIdx.y;   // grid (104, 32), block 256
  if (tvb >= 100) {                             // pad blocks: zero 256 pad rows
    for (int j = (tvb - 100) * 256 + threadIdx.x; j < 2048; j += 1024) {
      int row = j >> 3, c = j & 7;              // 256 rows x 8 uint4
      int tvrow = (row < 100) ? row : (6400 + row);
      uint4 z; z.x = z.y = z.z = z.w = 0u;
      *(uint4*)(xmr + ((size_t)n * NPADT + tvrow) * 64 + c * 8) = z;
    }
    return;
  }
  const int tvl = threadIdx.x & 63, q = threadIdx.x >> 6;  // 4 quads of 16 cin
  const int tv = tvb * 64 + tvl;
  const float* xp = x + ((size_t)n * 64 + q * 16) * TV + tv;
  const float* mp = mask + ((size_t)n * 64 + q * 16) * TV + tv;
  u16 vals[16];
  float msacc = 0.f;
#pragma unroll
  for (int j = 0; j < 16; ++j) {                // coalesced: lanes = consecutive tv
    float xv = xp[(size_t)j * TV];
    float mv = mp[(size_t)j * TV];
    msacc += mv;
    vals[j] = f2bf(xv * mv);
  }
  uint4 lo, hi;
  lo.x = vals[0] | ((u32)vals[1] << 16);  lo.y = vals[2] | ((u32)vals[3] << 16);
  lo.z = vals[4] | ((u32)vals[5] << 16);  lo.w = vals[6] | ((u32)vals[7] << 16);
  hi.x = vals[8] | ((u32)vals[9] << 16);  hi.y = vals[10] | ((u32)vals[11] << 16);
  hi.z = vals[12] | ((u32)vals[13] << 16); hi.w = vals[14] | ((u32)vals[15] << 16);
  u16* dst = xmr + ((size_t)n * NPADT + 100 + tv) * 64 + q * 16;
  *(uint4*)dst = lo;
  *(uint4*)(dst + 8) = hi;
  __shared__ float red[4][64];
  red[q][tvl] = msacc;
  __syncthreads();
  if (q == 0) msum[n * TV + tv] = red[0][tvl] + red[1][tvl] + red[2][tvl] + red[3][tvl];
}

// ---- wb[kc][k=dt*64+cin], bf16, 16B-slot XOR pre-swizzle (by (kc>>1)&3) -----
__global__ void k_w(const float* __restrict__ weight, u16* __restrict__ wb) {
  int i = blockIdx.x * 256 + threadIdx.x;      // 110592
  if (i >= 110592) return;
  int kc = i / KDIM, k = i % KDIM;
  int cin = k & 63, dt = k >> 6;
  float v = weight[(kc * 64 + cin) * 9 + dt];
  int phys = (k & ~31) | ((((k >> 3) & 3) ^ ((kc >> 1) & 3)) << 3) | (k & 7);
  wb[kc * KDIM + phys] = f2bf(v);
}

// ---- per (n, t-pair): upd -> s, mask_ratio, m_bool, Bc ----------------------
// 2 t per 64-thread block: lanes 0-24 -> t0, lanes 32-56 -> t1 (r18: lane use 2x).
__global__ void k_prep(const float* __restrict__ msum, const float* __restrict__ A_g,
                       float* __restrict__ s_ws, float* __restrict__ mr_ws,
                       float* __restrict__ mb_ws, float* __restrict__ Bc_ws) {
  int b = blockIdx.x;                          // 4096 = n*128 + tp
  int n = b >> 7, tp = b & 127;
  int tid = threadIdx.x;                       // 64
  int half = tid >> 5, l = tid & 31;
  int t = tp * 2 + half;
  __shared__ float uc[2][25];
  if (l < 25) {
    float upd = 0.f;
    for (int dt = 0; dt < 9; ++dt) {
      int tt = t + dt - 4;
      if (tt >= 0 && tt < 256) upd += msum[n * TV + tt * 25 + l];
    }
    float u_c = fminf(fmaxf(upd, 0.f), 1.f);
    float ratio = 576.f / (upd + 1e-8f);
    s_ws[n * TV + t * 25 + l] = ratio * u_c * u_c;  // coeff of raw in out
    uc[half][l] = u_c;
  }
  __syncthreads();
  if (l < 25) {
    int w = l;
    float M = 0.f;
    for (int k = 0; k < 3; ++k) {
      float acc = 0.f;
      for (int v = 0; v < 25; ++v) acc += uc[half][v] * A_g[(k * 25 + v) * 25 + w];
      Bc_ws[((size_t)(n * 3 + k) * 256 + t) * 25 + w] = acc;
      M += acc;
    }
    float mbv = (M != 0.f) ? 1.f : 0.f;
    mr_ws[n * TV + t * 25 + w] = mbv / (M + 1e-8f);
    mb_ws[n * TV + t * 25 + w] = mbv;
  }
}

// ---- FUSED: implicit-GEMM + MFMA (k,v)-contraction + coalesced epilogue -----
// Block (tg, n) via bijective XCD swizzle. 512 threads, 8 waves = 4(M) x 2(N);
// 2-buffer A-ring (VMCNT(0)+barrier per step, r13-proven); all epilogue misc
// staged in prologue into non-aliased LDS.
__global__ __launch_bounds__(512, 4) void k_fused(
    const u16* __restrict__ xmr, const u16* __restrict__ wb,
    const float* __restrict__ s_g, const float* __restrict__ A_g,
    const float* __restrict__ Bc_g, const float* __restrict__ mr_g,
    const float* __restrict__ mb_g, const float* __restrict__ bias_g,
    float* __restrict__ out) {
  __shared__ __align__(16) char ring[73824];

  const int tid = threadIdx.x;
  // XCD swizzle: nwg = 2048 = 8 XCDs x 256; bijective since 2048 % 8 == 0.
  const int flat = blockIdx.y * 64 + blockIdx.x;
  const int swz = (flat & 7) * 256 + (flat >> 3);
  const int tg = swz & 63;                    // 0..63 (4-t group)
  const int n = swz >> 6;                     // 0..31
  const int T = tg * 100;                     // window start (padded coords)
  const int lane = tid & 63, wid = tid >> 6;
  const int wm = wid >> 1, wn = wid & 1;
  const int lrow = lane & 15, lgrp = lane >> 4;
  const int nf = 4 - wn, colb = wn * 64;

  const u16* xmn = xmr + (size_t)n * NPADT * 64;
  u16* xwin = (u16*)(ring);
  u16*   Abu   = (u16*)(ring + L_AB);  // [3k][2nt][16w][32v] bf16 B-frag layout
  float* Bcsf  = (float*)(ring + L_BCS);
  float* mrsf  = (float*)(ring + L_MRS);
  float* biasf = (float*)(ring + L_BIAS);
  float* ssf   = (float*)(ring + L_SS);
  float* mbsf  = (float*)(ring + L_MBS);

  f32x4 acc[3][4] = {};

  // A staging helper: 12 tile-loads spread as waves 0-3: 2, waves 4-7: 1.
  auto stageA = [&](int buf, int ks) {
    u16* abase = (u16*)(ring + L_ARING + buf * 12288);
#pragma unroll
    for (int j = 0; j < 2; ++j) {
      int task = wid + j * 8;
      if (task < 12) {
        const u16* src = wb + (size_t)(task * 16 + (lane >> 2)) * KDIM + ks * 32 + (lane & 3) * 8;
        gload_lds16(src, abase + task * 512);
      }
    }
  };

  // ---- prologue: B window (39 gloads) + A(0) + ALL epilogue misc ------------
  {
    // LDS[row][slot] = global[row][slot ^ (row&7)] in WINDOW coords.
    const int srow_g = lane >> 3, sl = (lane & 7) ^ (lane >> 3);  // per-lane
    for (int t = wid; t < 39; t += 8) {
      const u16* src = xmn + ((size_t)(T + t * 8 + srow_g) * 64 + sl * 8);
      gload_lds16(src, xwin + t * 512);
    }
    stageA(0, 0);
    // misc: latency hides under the window gloads above
    for (int i = tid; i < 3072; i += 512) {
      int kk = i >> 10, r = i & 1023;
      int nt = r >> 9, rr = r & 511, wl = rr >> 5, v = rr & 31;
      int w = nt * 16 + wl;
      float val = (v < 25 && w < 25) ? A_g[(kk * 25 + v) * 25 + w] : 0.f;
      Abu[i] = f2bf(val);
    }
    if (tid < 300) {
      int k = tid / 100, t = (tid % 100) / 25, w = tid % 25;
      Bcsf[tid] = Bc_g[((size_t)(n * 3 + k) * 256 + tg * 4 + t) * 25 + w];
    }
    if (tid < 100) {
      mrsf[tid] = mr_g[n * TV + T + tid];
      ssf[tid]  = s_g[n * TV + T + tid];
      mbsf[tid] = mb_g[n * TV + T + tid];
    }
    if (tid >= 256 && tid < 448) biasf[tid - 256] = bias_g[tid - 256];
  }
  __syncthreads();                     // drains vmcnt+lgkmcnt: gloads + ds_writes

  // ---- K-loop: 18 steps; 2-buffer A-ring, 1 drain+barrier per step ----------
  for (int ks = 0; ks < 18; ++ks) {
    const int cur = ks & 1;
    if (ks < 17) stageA(cur ^ 1, ks + 1);

    const u16* abuf = (const u16*)(ring + L_ARING + cur * 12288);
    short8 af[3];
#pragma unroll
    for (int m = 0; m < 3; ++m) {
      int arow = wm * 48 + m * 16 + lrow;
      af[m] = *(const short8*)&abuf[arow * 32 + ((lgrp ^ ((arow >> 1) & 3)) << 3)];
    }
    const int dt = ks >> 1;
    const int rbase = 100 + (dt - 4) * 25 + colb + lrow;   // window row for ct=0
    const int slb = (ks & 1) * 4 + lgrp;                   // logical 16B slot
#pragma unroll
    for (int ct = 0; ct < 4; ++ct) {
      if (ct < nf) {
        int srow = rbase + ct * 16;
        short8 bfr = *(const short8*)&xwin[srow * 64 + ((slb ^ (srow & 7)) << 3)];
#pragma unroll
        for (int m = 0; m < 3; ++m)
          acc[m][ct] = __builtin_amdgcn_mfma_f32_16x16x32_bf16(af[m], bfr, acc[m][ct], 0, 0, 0);
      }
    }

    if (ks < 17) {
      VMCNT(0);                        // own A(ks+1) loads landed
      __builtin_amdgcn_s_barrier();    // all waves done reading abuf[cur]
      asm volatile("" ::: "memory");
    }
  }

  // ---- epilogue: zero Pl (aliases xwin), then MFMA contraction --------------
  __syncthreads();                     // all xwin/abuf reads done; safe to alias
  u16* Plu = (u16*)ring;               // [64][168]: tcol = t*40+v, pads zero
  {
    uint4 z; z.x = z.y = z.z = z.w = 0u;
    for (int i = tid; i < 1344; i += 512) ((uint4*)ring)[i] = z;  // zero Pl
  }
  __syncthreads();

  // y(ct,w) = sum_v P(ct,v) * A(v,w), per-k
  f32x4 yacc[2][2] = {};
  for (int k = 0; k < 3; ++k) {
    // stage Pl_k = bf16(acc * s) for rows of this k
#pragma unroll
    for (int m = 0; m < 3; ++m) {
      int R = wm * 48 + m * 16 + lgrp * 4;
      if ((R >> 6) == k) {
        int cb = R & 63;
#pragma unroll
        for (int ct = 0; ct < 4; ++ct) {
          if (ct < nf) {
            int col = colb + ct * 16 + lrow;
            if (col < 100) {
              int t = col / 25, v = col - t * 25;
              float sv = ssf[col];
              int tc = t * 40 + v;
#pragma unroll
              for (int r = 0; r < 4; ++r)
                Plu[(cb + r) * 168 + tc] = f2bf(acc[m][ct][r] * sv);
            }
          }
        }
      }
    }
    __syncthreads();
    // contraction MFMAs: wave owns M-tiles {wid*2, wid*2+1} (16 tiles of 16 ct)
    short8 pb[2];
#pragma unroll
    for (int nt = 0; nt < 2; ++nt)
      pb[nt] = *(const short8*)&Abu[((k * 2 + nt) * 16 + lrow) * 32 + lgrp * 8];
#pragma unroll
    for (int mi = 0; mi < 2; ++mi) {
      int mt = wid * 2 + mi;
      // A-row = mt*16 + lrow = ct; c = mt*4 + (lrow>>2), t = lrow&3
      const short8 pa = *(const short8*)
          &Plu[(mt * 4 + (lrow >> 2)) * 168 + (lrow & 3) * 40 + lgrp * 8];
#pragma unroll
      for (int nt = 0; nt < 2; ++nt)
        yacc[mi][nt] = __builtin_amdgcn_mfma_f32_16x16x32_bf16(pa, pb[nt], yacc[mi][nt], 0, 0, 0);
    }
    __syncthreads();                   // before next k overwrites Pl
  }

  // ---- finalize + transposed coalesced y writes ----------------------------
  // yacc[mi][nt][r]: ct = (wid*2+mi)*16 + lgrp*4 + r -> c = wid*8+mi*4+lgrp,
  // t = r; col w = nt*16 + lrow.
  float (*Ysf)[104] = (float(*)[104])ring;     // aliases Pl, barrier-separated
  const size_t base_n = (size_t)(n * 64) * 6400 + T;
#pragma unroll
  for (int half = 0; half < 2; ++half) {
    __syncthreads();
    if ((wid >> 2) == half) {
#pragma unroll
      for (int mi = 0; mi < 2; ++mi) {
        int c = wid * 8 + mi * 4 + lgrp;       // 0..63
#pragma unroll
        for (int nt = 0; nt < 2; ++nt) {
          int w = nt * 16 + lrow;
          if (w < 25) {
#pragma unroll
            for (int r = 0; r < 4; ++r) {
              float bt = biasf[c] * Bcsf[r * 25 + w] +
                         biasf[64 + c] * Bcsf[100 + r * 25 + w] +
                         biasf[128 + c] * Bcsf[200 + r * 25 + w];
              Ysf[c & 31][r * 25 + w] = (yacc[mi][nt][r] + bt) * mrsf[r * 25 + w];
            }
          }
        }
      }
    }
    __syncthreads();
    for (int i = tid; i < 3200; i += 512) {
      int ch = i / 100, j = i % 100;
      out[base_n + (size_t)(half * 32 + ch) * 6400 + j] = Ysf[ch][j];
    }
  }

  // m_bool: c-independent broadcast, direct coalesced stores
  for (int i = tid; i < 6400; i += 512) {
    int cc = i / 100, j = i % 100;
    out[MB_OFF + base_n + (size_t)cc * 6400 + j] = mbsf[j];
  }
}

extern "C" void kernel_launch(void* const* d_in, const int* in_sizes, int n_in,
                              void* d_out, int out_size, void* d_ws, size_t ws_size,
                              hipStream_t stream) {
  const float* x      = (const float*)d_in[0];
  const float* A      = (const float*)d_in[1];
  const float* mask   = (const float*)d_in[2];
  const float* weight = (const float*)d_in[3];
  const float* bias   = (const float*)d_in[4];
  float* out = (float*)d_out;
  char* ws = (char*)d_ws;

  u16*   xmr   = (u16*)(ws);
  u16*   wb    = (u16*)(ws + OFF_WB);
  float* msum  = (float*)(ws + OFF_MSUM);
  float* s_ws  = (float*)(ws + OFF_S);
  float* mr_ws = (float*)(ws + OFF_MR);
  float* mb_ws = (float*)(ws + OFF_MB);
  float* Bc_ws = (float*)(ws + OFF_BC);

  k_xmT<<<dim3(104, 32), 256, 0, stream>>>(x, mask, xmr, msum);
  k_w<<<432, 256, 0, stream>>>(weight, wb);
  k_prep<<<4096, 64, 0, stream>>>(msum, A, s_ws, mr_ws, mb_ws, Bc_ws);

  hipMemcpyAsync(out + Y_SIZE, A, 1875 * sizeof(float),
                 hipMemcpyDeviceToDevice, stream);

  k_fused<<<dim3(64, 32), 512, 0, stream>>>(xmr, wb, s_ws, A, Bc_ws, mr_ws,
                                            mb_ws, bias, out);
}

// Round 19
// 115.880 us; speedup vs baseline: 1.7606x; 1.0349x over previous
//
#include <hip/hip_runtime.h>

// PartialGConv: partial temporal conv (TK=9, pad 4) + mask-ratio + graph einsum.
// FUSED kernel (r18 structure): bf16 implicit-GEMM (MFMA 16x16x32, BM=192 x
// BN=112(4t, 100 useful) x K=576), once-staged B window, 2-buffer LDS A-ring,
// prologue-staged epilogue misc, bijective XCD swizzle, 2 blocks/CU.
// r19: single-pass Pl[192][168] contraction (6 barriers -> 2, no k-guard
// divergence, 12 clustered MFMAs) + m_bool stores hoisted before the K-loop
// (drain under compute instead of serializing at the tail).
//
// ws layout (bytes):
//   xmr  u16[32][6656][64]  @0          x*mask bf16 row-major, padded rows
//   wb   u16[192][576]      @27,262,976 weights bf16, k=dt*64+cin, 16B-slot swizzled
//   msum f32[32][6400]      @27,484,160 sum_cin mask
//   s    f32[32][6400]      @28,303,360 576/(upd+eps)*uc^2
//   mr   f32[32][6400]      @29,122,560 mask_ratio
//   mb   f32[32][6400]      @29,941,760 m_bool
//   Bc   f32[32][3][256][25]@30,760,960 sum_v uc*A[k,v,w]

typedef unsigned short u16;
typedef unsigned int u32;
typedef short short8 __attribute__((ext_vector_type(8)));
typedef float f32x4 __attribute__((ext_vector_type(4)));

#define TV 6400
#define KC 192
#define KDIM 576
#define NPADT 6656          // 100 front pad + 6400 + 156 back pad
#define Y_SIZE 13107200
#define MB_OFF 13109075     // Y_SIZE + 1875

#define OFF_WB   27262976
#define OFF_MSUM 27484160
#define OFF_S    28303360
#define OFF_MR   29122560
#define OFF_MB   29941760
#define OFF_BC   30760960

// LDS map (73,824 B total -> 2 blocks/CU). K-loop: xwin [0,39936) =
// 312 rows x 128B; A-ring [39936,64512) = 2 x 12,288.
// Misc (PROLOGUE-staged, never aliased): Ab @64512 (6144) | Bcs @70656 (1200)
// | mrs @71856 (400) | bias @72256 (768) | ss @73024 (400) | mbs @73424 (400).
// Epilogue aliases (xwin+A-ring): Pl u16[192][168] @0 (64,512 = exactly the
// [0, L_AB) region); Ys f32[32][104] @0 (13,312).
#define L_ARING 39936
#define L_AB    64512
#define L_BCS   70656
#define L_MRS   71856
#define L_BIAS  72256
#define L_SS    73024
#define L_MBS   73424

#define VMCNT(N) asm volatile("s_waitcnt vmcnt(" #N ")" ::: "memory")

__device__ __forceinline__ u16 f2bf(float f) {
  u32 u = __builtin_bit_cast(u32, f);
  u = (u + 0x7FFFu + ((u >> 16) & 1u)) >> 16;   // RTNE
  return (u16)u;
}
__device__ __forceinline__ float bf2f(u16 h) {
  return __builtin_bit_cast(float, (u32)h << 16);
}
__device__ __forceinline__ void gload_lds16(const u16* g, u16* l) {
  __builtin_amdgcn_global_load_lds(
      (const __attribute__((address_space(1))) u32*)(const void*)g,
      (__attribute__((address_space(3))) u32*)(void*)l, 16, 0, 0);
}

// ---- xmr = bf16(x*mask) row-major [tvp][64] + msum; pads via extra blocks ---
__global__ void k_xmT(const float* __restrict__ x, const float* __restrict__ mask,
                      u16* __restrict__ xmr, float* __restrict__ msum) {
  const int tvb = blockIdx.x, n = blockIdx.y;   // grid (104, 32), block 256
  if (tvb >= 100) {                             // pad blocks: zero 256 pad rows
    for (int j = (tvb - 100) * 256 + threadIdx.x; j < 2048; j += 1024) {
      int row = j >> 3, c = j & 7;              // 256 rows x 8 uint4
      int tvrow = (row < 100) ? row : (6400 + row);
      uint4 z; z.x = z.y = z.z = z.w = 0u;
      *(uint4*)(xmr + ((size_t)n * NPADT + tvrow) * 64 + c * 8) = z;
    }
    return;
  }
  const int tvl = threadIdx.x & 63, q = threadIdx.x >> 6;  // 4 quads of 16 cin
  const int tv = tvb * 64 + tvl;
  const float* xp = x + ((size_t)n * 64 + q * 16) * TV + tv;
  const float* mp = mask + ((size_t)n * 64 + q * 16) * TV + tv;
  u16 vals[16];
  float msacc = 0.f;
#pragma unroll
  for (int j = 0; j < 16; ++j) {                // coalesced: lanes = consecutive tv
    float xv = xp[(size_t)j * TV];
    float mv = mp[(size_t)j * TV];
    msacc += mv;
    vals[j] = f2bf(xv * mv);
  }
  uint4 lo, hi;
  lo.x = vals[0] | ((u32)vals[1] << 16);  lo.y = vals[2] | ((u32)vals[3] << 16);
  lo.z = vals[4] | ((u32)vals[5] << 16);  lo.w = vals[6] | ((u32)vals[7] << 16);
  hi.x = vals[8] | ((u32)vals[9] << 16);  hi.y = vals[10] | ((u32)vals[11] << 16);
  hi.z = vals[12] | ((u32)vals[13] << 16); hi.w = vals[14] | ((u32)vals[15] << 16);
  u16* dst = xmr + ((size_t)n * NPADT + 100 + tv) * 64 + q * 16;
  *(uint4*)dst = lo;
  *(uint4*)(dst + 8) = hi;
  __shared__ float red[4][64];
  red[q][tvl] = msacc;
  __syncthreads();
  if (q == 0) msum[n * TV + tv] = red[0][tvl] + red[1][tvl] + red[2][tvl] + red[3][tvl];
}

// ---- wb[kc][k=dt*64+cin], bf16, 16B-slot XOR pre-swizzle (by (kc>>1)&3) -----
__global__ void k_w(const float* __restrict__ weight, u16* __restrict__ wb) {
  int i = blockIdx.x * 256 + threadIdx.x;      // 110592
  if (i >= 110592) return;
  int kc = i / KDIM, k = i % KDIM;
  int cin = k & 63, dt = k >> 6;
  float v = weight[(kc * 64 + cin) * 9 + dt];
  int phys = (k & ~31) | ((((k >> 3) & 3) ^ ((kc >> 1) & 3)) << 3) | (k & 7);
  wb[kc * KDIM + phys] = f2bf(v);
}

// ---- per (n, t-pair): upd -> s, mask_ratio, m_bool, Bc ----------------------
// 2 t per 64-thread block: lanes 0-24 -> t0, lanes 32-56 -> t1.
__global__ void k_prep(const float* __restrict__ msum, const float* __restrict__ A_g,
                       float* __restrict__ s_ws, float* __restrict__ mr_ws,
                       float* __restrict__ mb_ws, float* __restrict__ Bc_ws) {
  int b = blockIdx.x;                          // 4096 = n*128 + tp
  int n = b >> 7, tp = b & 127;
  int tid = threadIdx.x;                       // 64
  int half = tid >> 5, l = tid & 31;
  int t = tp * 2 + half;
  __shared__ float uc[2][25];
  if (l < 25) {
    float upd = 0.f;
    for (int dt = 0; dt < 9; ++dt) {
      int tt = t + dt - 4;
      if (tt >= 0 && tt < 256) upd += msum[n * TV + tt * 25 + l];
    }
    float u_c = fminf(fmaxf(upd, 0.f), 1.f);
    float ratio = 576.f / (upd + 1e-8f);
    s_ws[n * TV + t * 25 + l] = ratio * u_c * u_c;  // coeff of raw in out
    uc[half][l] = u_c;
  }
  __syncthreads();
  if (l < 25) {
    int w = l;
    float M = 0.f;
    for (int k = 0; k < 3; ++k) {
      float acc = 0.f;
      for (int v = 0; v < 25; ++v) acc += uc[half][v] * A_g[(k * 25 + v) * 25 + w];
      Bc_ws[((size_t)(n * 3 + k) * 256 + t) * 25 + w] = acc;
      M += acc;
    }
    float mbv = (M != 0.f) ? 1.f : 0.f;
    mr_ws[n * TV + t * 25 + w] = mbv / (M + 1e-8f);
    mb_ws[n * TV + t * 25 + w] = mbv;
  }
}

// ---- FUSED: implicit-GEMM + MFMA (k,v)-contraction + coalesced epilogue -----
// Block (tg, n) via bijective XCD swizzle. 512 threads, 8 waves = 4(M) x 2(N);
// 2-buffer A-ring; prologue-staged misc; m_bool overlapped with K-loop;
// single-pass Pl[192][168] contraction.
__global__ __launch_bounds__(512, 4) void k_fused(
    const u16* __restrict__ xmr, const u16* __restrict__ wb,
    const float* __restrict__ s_g, const float* __restrict__ A_g,
    const float* __restrict__ Bc_g, const float* __restrict__ mr_g,
    const float* __restrict__ mb_g, const float* __restrict__ bias_g,
    float* __restrict__ out) {
  __shared__ __align__(16) char ring[73824];

  const int tid = threadIdx.x;
  // XCD swizzle: nwg = 2048 = 8 XCDs x 256; bijective since 2048 % 8 == 0.
  const int flat = blockIdx.y * 64 + blockIdx.x;
  const int swz = (flat & 7) * 256 + (flat >> 3);
  const int tg = swz & 63;                    // 0..63 (4-t group)
  const int n = swz >> 6;                     // 0..31
  const int T = tg * 100;                     // window start (padded coords)
  const int lane = tid & 63, wid = tid >> 6;
  const int wm = wid >> 1, wn = wid & 1;
  const int lrow = lane & 15, lgrp = lane >> 4;
  const int nf = 4 - wn, colb = wn * 64;

  const u16* xmn = xmr + (size_t)n * NPADT * 64;
  u16* xwin = (u16*)(ring);
  u16*   Abu   = (u16*)(ring + L_AB);  // [3k][2nt][16w][32v] bf16 B-frag layout
  float* Bcsf  = (float*)(ring + L_BCS);
  float* mrsf  = (float*)(ring + L_MRS);
  float* biasf = (float*)(ring + L_BIAS);
  float* ssf   = (float*)(ring + L_SS);
  float* mbsf  = (float*)(ring + L_MBS);

  f32x4 acc[3][4] = {};

  // A staging helper: 12 tile-loads spread as waves 0-3: 2, waves 4-7: 1.
  auto stageA = [&](int buf, int ks) {
    u16* abase = (u16*)(ring + L_ARING + buf * 12288);
#pragma unroll
    for (int j = 0; j < 2; ++j) {
      int task = wid + j * 8;
      if (task < 12) {
        const u16* src = wb + (size_t)(task * 16 + (lane >> 2)) * KDIM + ks * 32 + (lane & 3) * 8;
        gload_lds16(src, abase + task * 512);
      }
    }
  };

  // ---- prologue: B window (39 gloads) + A(0) + ALL epilogue misc ------------
  {
    // LDS[row][slot] = global[row][slot ^ (row&7)] in WINDOW coords.
    const int srow_g = lane >> 3, sl = (lane & 7) ^ (lane >> 3);  // per-lane
    for (int t = wid; t < 39; t += 8) {
      const u16* src = xmn + ((size_t)(T + t * 8 + srow_g) * 64 + sl * 8);
      gload_lds16(src, xwin + t * 512);
    }
    stageA(0, 0);
    // misc: latency hides under the window gloads above
    for (int i = tid; i < 3072; i += 512) {
      int kk = i >> 10, r = i & 1023;
      int nt = r >> 9, rr = r & 511, wl = rr >> 5, v = rr & 31;
      int w = nt * 16 + wl;
      float val = (v < 25 && w < 25) ? A_g[(kk * 25 + v) * 25 + w] : 0.f;
      Abu[i] = f2bf(val);
    }
    if (tid < 300) {
      int k = tid / 100, t = (tid % 100) / 25, w = tid % 25;
      Bcsf[tid] = Bc_g[((size_t)(n * 3 + k) * 256 + tg * 4 + t) * 25 + w];
    }
    if (tid < 100) {
      mrsf[tid] = mr_g[n * TV + T + tid];
      ssf[tid]  = s_g[n * TV + T + tid];
      mbsf[tid] = mb_g[n * TV + T + tid];
    }
    if (tid >= 256 && tid < 448) biasf[tid - 256] = bias_g[tid - 256];
  }
  __syncthreads();                     // drains vmcnt+lgkmcnt: gloads + ds_writes

  const size_t base_n = (size_t)(n * 64) * 6400 + T;

  // m_bool: c-independent broadcast; issued HERE so the 52MB chip-wide write
  // drains under the K-loop (one-time retire wait at step-0's VMCNT(0)).
  for (int i = tid; i < 6400; i += 512) {
    int cc = i / 100, j = i % 100;
    out[MB_OFF + base_n + (size_t)cc * 6400 + j] = mbsf[j];
  }

  // ---- K-loop: 18 steps; 2-buffer A-ring, 1 drain+barrier per step ----------
  for (int ks = 0; ks < 18; ++ks) {
    const int cur = ks & 1;
    if (ks < 17) stageA(cur ^ 1, ks + 1);

    const u16* abuf = (const u16*)(ring + L_ARING + cur * 12288);
    short8 af[3];
#pragma unroll
    for (int m = 0; m < 3; ++m) {
      int arow = wm * 48 + m * 16 + lrow;
      af[m] = *(const short8*)&abuf[arow * 32 + ((lgrp ^ ((arow >> 1) & 3)) << 3)];
    }
    const int dt = ks >> 1;
    const int rbase = 100 + (dt - 4) * 25 + colb + lrow;   // window row for ct=0
    const int slb = (ks & 1) * 4 + lgrp;                   // logical 16B slot
#pragma unroll
    for (int ct = 0; ct < 4; ++ct) {
      if (ct < nf) {
        int srow = rbase + ct * 16;
        short8 bfr = *(const short8*)&xwin[srow * 64 + ((slb ^ (srow & 7)) << 3)];
#pragma unroll
        for (int m = 0; m < 3; ++m)
          acc[m][ct] = __builtin_amdgcn_mfma_f32_16x16x32_bf16(af[m], bfr, acc[m][ct], 0, 0, 0);
      }
    }

    if (ks < 17) {
      VMCNT(0);                        // own A(ks+1) loads landed
      __builtin_amdgcn_s_barrier();    // all waves done reading abuf[cur]
      asm volatile("" ::: "memory");
    }
  }

  // ---- epilogue: single-pass Pl[192][168] (aliases xwin+A-ring) ------------
  __syncthreads();                     // all xwin/abuf reads done; safe to alias
  u16* Plu = (u16*)ring;               // [192][168]: row = kc, tcol = t*40+v
  {
    uint4 z; z.x = z.y = z.z = z.w = 0u;
    for (int i = tid; i < 4032; i += 512) ((uint4*)ring)[i] = z;  // zero 64.5KB
  }
  __syncthreads();

  // P-stage: ALL kc rows at once (no k-guard, no divergence)
#pragma unroll
  for (int m = 0; m < 3; ++m) {
    int R = wm * 48 + m * 16 + lgrp * 4;       // global kc row base
#pragma unroll
    for (int ct = 0; ct < 4; ++ct) {
      if (ct < nf) {
        int col = colb + ct * 16 + lrow;
        if (col < 100) {
          int t = col / 25, v = col - t * 25;
          float sv = ssf[col];
          int tc = t * 40 + v;
#pragma unroll
          for (int r = 0; r < 4; ++r)
            Plu[(R + r) * 168 + tc] = f2bf(acc[m][ct][r] * sv);
        }
      }
    }
  }
  __syncthreads();

  // contraction: y(ct,w) = sum_{k,v} P * A — 12 clustered MFMAs per wave
  f32x4 yacc[2][2] = {};
#pragma unroll
  for (int k = 0; k < 3; ++k) {
    short8 pb[2];
#pragma unroll
    for (int nt = 0; nt < 2; ++nt)
      pb[nt] = *(const short8*)&Abu[((k * 2 + nt) * 16 + lrow) * 32 + lgrp * 8];
#pragma unroll
    for (int mi = 0; mi < 2; ++mi) {
      int mt = wid * 2 + mi;
      // pa row = k*64 + c-local (mt*4 + lrow>>2); k-dim = t*40 + v (lgrp*8..)
      const short8 pa = *(const short8*)
          &Plu[(k * 64 + mt * 4 + (lrow >> 2)) * 168 + (lrow & 3) * 40 + lgrp * 8];
#pragma unroll
      for (int nt = 0; nt < 2; ++nt)
        yacc[mi][nt] = __builtin_amdgcn_mfma_f32_16x16x32_bf16(pa, pb[nt], yacc[mi][nt], 0, 0, 0);
    }
  }

  // ---- finalize + transposed coalesced y writes ----------------------------
  // yacc[mi][nt][r]: ct = (wid*2+mi)*16 + lgrp*4 + r -> c = wid*8+mi*4+lgrp,
  // t = r; col w = nt*16 + lrow.
  float (*Ysf)[104] = (float(*)[104])ring;     // aliases Pl, barrier-separated
#pragma unroll
  for (int half = 0; half < 2; ++half) {
    __syncthreads();                   // contraction Pl reads / prior Ys done
    if ((wid >> 2) == half) {
#pragma unroll
      for (int mi = 0; mi < 2; ++mi) {
        int c = wid * 8 + mi * 4 + lgrp;       // 0..63
#pragma unroll
        for (int nt = 0; nt < 2; ++nt) {
          int w = nt * 16 + lrow;
          if (w < 25) {
#pragma unroll
            for (int r = 0; r < 4; ++r) {
              float bt = biasf[c] * Bcsf[r * 25 + w] +
                         biasf[64 + c] * Bcsf[100 + r * 25 + w] +
                         biasf[128 + c] * Bcsf[200 + r * 25 + w];
              Ysf[c & 31][r * 25 + w] = (yacc[mi][nt][r] + bt) * mrsf[r * 25 + w];
            }
          }
        }
      }
    }
    __syncthreads();
    for (int i = tid; i < 3200; i += 512) {
      int ch = i / 100, j = i % 100;
      out[base_n + (size_t)(half * 32 + ch) * 6400 + j] = Ysf[ch][j];
    }
  }
}

extern "C" void kernel_launch(void* const* d_in, const int* in_sizes, int n_in,
                              void* d_out, int out_size, void* d_ws, size_t ws_size,
                              hipStream_t stream) {
  const float* x      = (const float*)d_in[0];
  const float* A      = (const float*)d_in[1];
  const float* mask   = (const float*)d_in[2];
  const float* weight = (const float*)d_in[3];
  const float* bias   = (const float*)d_in[4];
  float* out = (float*)d_out;
  char* ws = (char*)d_ws;

  u16*   xmr   = (u16*)(ws);
  u16*   wb    = (u16*)(ws + OFF_WB);
  float* msum  = (float*)(ws + OFF_MSUM);
  float* s_ws  = (float*)(ws + OFF_S);
  float* mr_ws = (float*)(ws + OFF_MR);
  float* mb_ws = (float*)(ws + OFF_MB);
  float* Bc_ws = (float*)(ws + OFF_BC);

  k_xmT<<<dim3(104, 32), 256, 0, stream>>>(x, mask, xmr, msum);
  k_w<<<432, 256, 0, stream>>>(weight, wb);
  k_prep<<<4096, 64, 0, stream>>>(msum, A, s_ws, mr_ws, mb_ws, Bc_ws);

  hipMemcpyAsync(out + Y_SIZE, A, 1875 * sizeof(float),
                 hipMemcpyDeviceToDevice, stream);

  k_fused<<<dim3(64, 32), 512, 0, stream>>>(xmr, wb, s_ws, A, Bc_ws, mr_ws,
                                            mb_ws, bias, out);
}